// Round 6
// baseline (399.838 us; speedup 1.0000x reference)
//
#include <hip/hip_runtime.h>

#define B_ 2
#define S_ 2048
#define C_ 1024
#define H_ 16
#define D_ 64

typedef _Float16 f16;
typedef _Float16 half8 __attribute__((ext_vector_type(8)));
typedef _Float16 half4v __attribute__((ext_vector_type(4)));
typedef float floatx4 __attribute__((ext_vector_type(4)));

#define LD4F(p) (*reinterpret_cast<const float4*>(p))
#define LD16U(p) (*reinterpret_cast<const uint4*>(p))
#define EXP2F(x) __builtin_amdgcn_exp2f(x)

// async global->LDS 16B (dest must be linear: wave-uniform base + lane*16)
__device__ __forceinline__ void gload16(const f16* g, f16* l) {
    __builtin_amdgcn_global_load_lds(
        (const __attribute__((address_space(1))) void*)g,
        (__attribute__((address_space(3))) void*)l, 16, 0, 0);
}

// ---------------------------------------------------------------------------
// Convert fp32 inputs to fp16 workspace: [x (4M) | Wq | Wk | Wv | Wo (1M each)]
// ---------------------------------------------------------------------------
__global__ __launch_bounds__(256)
void convert_inputs(const float* __restrict__ x,
                    const float* __restrict__ Wq, const float* __restrict__ Wk,
                    const float* __restrict__ Wv, const float* __restrict__ Wo,
                    f16* __restrict__ dst)
{
    const size_t XN = (size_t)B_ * S_ * C_;
    const size_t WN = (size_t)C_ * C_;
    size_t i = (size_t)blockIdx.x * 256 + threadIdx.x;
    size_t e = i * 4;
    if (e >= XN + 4 * WN) return;
    const float* s; size_t o;
    if (e < XN) { s = x; o = e; }
    else {
        size_t j = e - XN;
        int w = (int)(j >> 20);
        s = (w == 0) ? Wq : (w == 1) ? Wk : (w == 2) ? Wv : Wo;
        o = j & (WN - 1);
    }
    float4 val = LD4F(&s[o]);
    half4v hv;
    hv[0] = (f16)val.x; hv[1] = (f16)val.y; hv[2] = (f16)val.z; hv[3] = (f16)val.w;
    *reinterpret_cast<half4v*>(&dst[e]) = hv;
}

// ---------------------------------------------------------------------------
// QKV projection, m97-style: global_load_lds 16B staging, linear [128][32]
// LDS, 2-barrier K-loop, 4 waves x (64x64 via 4x4 16x16x32 frags).
// Q output is pre-scaled by 0.125*log2(e) so attention can use exp2 directly.
// ---------------------------------------------------------------------------
__global__ __launch_bounds__(256)
void qkv_gemm_h(const f16* __restrict__ xh, const f16* __restrict__ Wbase,
                const float* __restrict__ bq, const float* __restrict__ bk,
                const float* __restrict__ bv,
                f16* __restrict__ qo, f16* __restrict__ ko, f16* __restrict__ vo)
{
    const int which = blockIdx.z;
    const f16* W      = Wbase + (size_t)which * C_ * C_;
    const float* bias = (which == 0) ? bq : (which == 1) ? bk : bv;
    f16* out          = (which == 0) ? qo : (which == 1) ? ko : vo;
    const float qscale = (which == 0) ? 0.18033688f : 1.0f;   // 0.125 * log2(e)

    const int mb = blockIdx.x * 128;
    const int nb = blockIdx.y * 128;
    const int tid = threadIdx.x;
    const int lane = tid & 63;
    const int wid = tid >> 6;
    const int wr = wid >> 1, wc = wid & 1;
    const int l15 = lane & 15, g = lane >> 4;

    __shared__ __align__(16) f16 As[128 * 32];
    __shared__ __align__(16) f16 Bs[128 * 32];

    floatx4 acc[4][4];
#pragma unroll
    for (int m = 0; m < 4; ++m)
#pragma unroll
        for (int n = 0; n < 4; ++n) acc[m][n] = (floatx4){0.f, 0.f, 0.f, 0.f};

    for (int k0 = 0; k0 < C_; k0 += 32) {
        __syncthreads();   // all waves done reading previous tile
#pragma unroll
        for (int p = 0; p < 2; ++p) {
            int i2 = tid + 256 * p;            // 0..511
            int row = i2 >> 2, c4 = i2 & 3;    // 128 rows x 4 chunks of 8 halves
            gload16(&xh[(size_t)(mb + row) * C_ + k0 + c4 * 8], &As[i2 * 8]);
            gload16(&W [(size_t)(nb + row) * C_ + k0 + c4 * 8], &Bs[i2 * 8]);
        }
        __syncthreads();   // vmcnt(0) drain -> tiles resident

        half8 af[4];
#pragma unroll
        for (int m = 0; m < 4; ++m)
            af[m] = *reinterpret_cast<const half8*>(&As[(wr * 64 + m * 16 + l15) * 32 + g * 8]);
#pragma unroll
        for (int n = 0; n < 4; ++n) {
            half8 bf = *reinterpret_cast<const half8*>(&Bs[(wc * 64 + n * 16 + l15) * 32 + g * 8]);
#pragma unroll
            for (int m = 0; m < 4; ++m)
                acc[m][n] = __builtin_amdgcn_mfma_f32_16x16x32_f16(af[m], bf, acc[m][n], 0, 0, 0);
        }
    }

#pragma unroll
    for (int n = 0; n < 4; ++n) {
        int col = nb + wc * 64 + n * 16 + l15;
        float bb = bias[col];
        int h = col >> 6, d = col & 63;
#pragma unroll
        for (int m = 0; m < 4; ++m)
#pragma unroll
            for (int r = 0; r < 4; ++r) {
                int row = mb + wr * 64 + m * 16 + g * 4 + r;
                int b = row >> 11, s = row & (S_ - 1);
                out[(((size_t)b * H_ + h) * S_ + s) * D_ + d] = (f16)((acc[m][n][r] + bb) * qscale);
            }
    }
}

// ---------------------------------------------------------------------------
// Flash attention, fp16 MFMA, exp2 softmax. grid=(32,32) XCD-remapped so
// each XCD owns 4 bh (K/V L2-resident). 4 waves x 16 Q-rows; KVBLK=64.
// K fragments load DIRECTLY from global (row-contiguous 16B, L2-hot) - no
// K LDS at all. V transposed into double-buffered LDS Vt[2][d][kv] via
// rotated scatter (conflict-free writes); single barrier per tile.
// V global loads for tile t+1 issued before compute of tile t (async-stage).
// ---------------------------------------------------------------------------
__global__ __launch_bounds__(256)
void attn_mfma(const f16* __restrict__ q, const f16* __restrict__ k,
               const f16* __restrict__ v, const int* __restrict__ mask,
               const float* __restrict__ rel, f16* __restrict__ ctx)
{
    const int flat = blockIdx.y * 32 + blockIdx.x;
    const int c = flat & 7, j = flat >> 3;
    const int bh = (c << 2) | (j >> 5);
    const int qb = (j & 31) * 64;

    const int b = bh >> 4, h = bh & 15;
    const f16* qh_ = q + (size_t)bh * S_ * D_;
    const f16* kh_ = k + (size_t)bh * S_ * D_;
    const f16* vh_ = v + (size_t)bh * S_ * D_;

    const int tid = threadIdx.x;
    const int lane = tid & 63;
    const int wid = tid >> 6;
    const int l15 = lane & 15, g = lane >> 4;

    __shared__ __align__(16) f16 Vt[2][64 * 72];    // [buf][d][kv], 144B rows
    __shared__ __align__(16) f16 Ps[4][16 * 72];    // per-wave P
    __shared__ float Prj[64][12];

    // staging coords for V (64 rows x 8 chunks of 8 halves, 2 passes)
    const int srow = tid >> 3;          // 0..31 (+32 second pass)
    const int sc8  = tid & 7;

    // Q fragments (pre-scaled by 0.125*log2e at qkv epilogue)
    const int qrow = qb + wid * 16 + l15;
    half8 aq0 = *reinterpret_cast<const half8*>(&qh_[(size_t)qrow * D_ + g * 8]);
    half8 aq1 = *reinterpret_cast<const half8*>(&qh_[(size_t)qrow * D_ + 32 + g * 8]);

    // rel projections for this wave's 16 rows
#pragma unroll
    for (int rr = 0; rr < 9; ++rr) {
        float p = 0.f;
#pragma unroll
        for (int jj = 0; jj < 8; ++jj) {
            p += (float)aq0[jj] * rel[rr * D_ + g * 8 + jj];
            p += (float)aq1[jj] * rel[rr * D_ + 32 + g * 8 + jj];
        }
        p += __shfl_xor(p, 16);
        p += __shfl_xor(p, 32);
        if (lane < 16) Prj[wid * 16 + l15][rr] = p;
    }
    float prj_lo[4], prj_hi[4];
#pragma unroll
    for (int r = 0; r < 4; ++r) {
        prj_lo[r] = Prj[wid * 16 + g * 4 + r][0];
        prj_hi[r] = Prj[wid * 16 + g * 4 + r][8];
    }

    floatx4 o[4];
    float mrun[4], lrun[4];
#pragma unroll
    for (int n = 0; n < 4; ++n) o[n] = (floatx4){0.f, 0.f, 0.f, 0.f};
#pragma unroll
    for (int r = 0; r < 4; ++r) { mrun[r] = -INFINITY; lrun[r] = 0.f; }

    // prologue: stage V tile 0 into Vt[0]
    {
        uint4 vr0 = LD16U(&vh_[(size_t)srow * D_ + sc8 * 8]);
        uint4 vr1 = LD16U(&vh_[(size_t)(32 + srow) * D_ + sc8 * 8]);
        const f16* vp0 = reinterpret_cast<const f16*>(&vr0);
        const f16* vp1 = reinterpret_cast<const f16*>(&vr1);
#pragma unroll
        for (int jj = 0; jj < 8; ++jj) {
            int dd = (jj + sc8) & 7;
            Vt[0][(sc8 * 8 + dd) * 72 + srow]      = vp0[dd];
            Vt[0][(sc8 * 8 + dd) * 72 + 32 + srow] = vp1[dd];
        }
    }
    __syncthreads();

    for (int jt = 0; jt < S_ / 64; ++jt) {
        const int jb = jt * 64;
        const int cur = jt & 1, nxt = cur ^ 1;

        // issue V loads for NEXT tile early (latency hides under compute)
        uint4 vr0, vr1;
        const bool pf = (jt + 1 < S_ / 64);
        if (pf) {
            const int jb2 = jb + 64;
            vr0 = LD16U(&vh_[(size_t)(jb2 + srow) * D_ + sc8 * 8]);
            vr1 = LD16U(&vh_[(size_t)(jb2 + 32 + srow) * D_ + sc8 * 8]);
        }

        // K fragments directly from global (B-frag = row-contiguous 16B)
        half8 kf0[4], kf1[4];
#pragma unroll
        for (int n = 0; n < 4; ++n) {
            const f16* kp = &kh_[(size_t)(jb + n * 16 + l15) * D_ + g * 8];
            kf0[n] = *reinterpret_cast<const half8*>(kp);
            kf1[n] = *reinterpret_cast<const half8*>(kp + 32);
        }

        // S = Q K^T (fp32 acc, log2-domain)
        floatx4 sc[4];
#pragma unroll
        for (int n = 0; n < 4; ++n) sc[n] = (floatx4){0.f, 0.f, 0.f, 0.f};
#pragma unroll
        for (int n = 0; n < 4; ++n) {
            sc[n] = __builtin_amdgcn_mfma_f32_16x16x32_f16(aq0, kf0[n], sc[n], 0, 0, 0);
            sc[n] = __builtin_amdgcn_mfma_f32_16x16x32_f16(aq1, kf1[n], sc[n], 0, 0, 0);
        }

        // rel bias + mask (fast path off-diagonal)
        float pvv[4][4];
        const bool diag = (jb >= qb - 64) && (jb <= qb + 64);
        if (!diag) {
            const float* pb = (jb > qb) ? prj_hi : prj_lo;
#pragma unroll
            for (int n = 0; n < 4; ++n) {
                int mv = mask[b * S_ + jb + n * 16 + l15];
#pragma unroll
                for (int r = 0; r < 4; ++r)
                    pvv[n][r] = mv ? (sc[n][r] + pb[r]) : -1.0e9f;
            }
        } else {
#pragma unroll
            for (int n = 0; n < 4; ++n) {
                int jg = jb + n * 16 + l15;
                int mv = mask[b * S_ + jg];
#pragma unroll
                for (int r = 0; r < 4; ++r) {
                    int ig = qb + wid * 16 + g * 4 + r;
                    int dp = jg - ig;
                    dp = dp < -4 ? -4 : (dp > 4 ? 4 : dp);
                    float val = sc[n][r] + Prj[wid * 16 + g * 4 + r][dp + 4];
                    pvv[n][r] = mv ? val : -1.0e9f;
                }
            }
        }

        // online softmax (exp2 domain)
#pragma unroll
        for (int r = 0; r < 4; ++r) {
            float mx = fmaxf(fmaxf(pvv[0][r], pvv[1][r]), fmaxf(pvv[2][r], pvv[3][r]));
            mx = fmaxf(mx, __shfl_xor(mx, 1));
            mx = fmaxf(mx, __shfl_xor(mx, 2));
            mx = fmaxf(mx, __shfl_xor(mx, 4));
            mx = fmaxf(mx, __shfl_xor(mx, 8));
            float mnew = fmaxf(mrun[r], mx);
            float scl = EXP2F(mrun[r] - mnew);
            float rs = 0.f;
#pragma unroll
            for (int n = 0; n < 4; ++n) {
                float e = EXP2F(pvv[n][r] - mnew);
                pvv[n][r] = e; rs += e;
            }
            rs += __shfl_xor(rs, 1); rs += __shfl_xor(rs, 2);
            rs += __shfl_xor(rs, 4); rs += __shfl_xor(rs, 8);
            lrun[r] = lrun[r] * scl + rs;
            mrun[r] = mnew;
#pragma unroll
            for (int n = 0; n < 4; ++n) o[n][r] *= scl;
        }

        // P -> wave-private LDS (fp16), then A-frags
#pragma unroll
        for (int n = 0; n < 4; ++n)
#pragma unroll
            for (int r = 0; r < 4; ++r)
                Ps[wid][(g * 4 + r) * 72 + n * 16 + l15] = (f16)pvv[n][r];

        half8 pa0 = *reinterpret_cast<const half8*>(&Ps[wid][l15 * 72 + g * 8]);
        half8 pa1 = *reinterpret_cast<const half8*>(&Ps[wid][l15 * 72 + 32 + g * 8]);

        // O += P V  (b128 B-frags from current Vt buffer)
#pragma unroll
        for (int n = 0; n < 4; ++n) {
            half8 bv0 = *reinterpret_cast<const half8*>(&Vt[cur][(n * 16 + l15) * 72 + g * 8]);
            half8 bv1 = *reinterpret_cast<const half8*>(&Vt[cur][(n * 16 + l15) * 72 + 32 + g * 8]);
            o[n] = __builtin_amdgcn_mfma_f32_16x16x32_f16(pa0, bv0, o[n], 0, 0, 0);
            o[n] = __builtin_amdgcn_mfma_f32_16x16x32_f16(pa1, bv1, o[n], 0, 0, 0);
        }

        // scatter-write next V tile (other buffer: no read/write race),
        // then the single per-tile barrier publishes it for all waves.
        if (pf) {
            const f16* vp0 = reinterpret_cast<const f16*>(&vr0);
            const f16* vp1 = reinterpret_cast<const f16*>(&vr1);
#pragma unroll
            for (int jj = 0; jj < 8; ++jj) {
                int dd = (jj + sc8) & 7;
                Vt[nxt][(sc8 * 8 + dd) * 72 + srow]      = vp0[dd];
                Vt[nxt][(sc8 * 8 + dd) * 72 + 32 + srow] = vp1[dd];
            }
        }
        __syncthreads();
    }

    // normalize + write ctx (B,S,C) fp16
#pragma unroll
    for (int n = 0; n < 4; ++n) {
        int dcol = n * 16 + l15;
#pragma unroll
        for (int r = 0; r < 4; ++r) {
            int srow2 = qb + wid * 16 + g * 4 + r;
            float val = o[n][r] / lrun[r];
            ctx[((size_t)(b * S_ + srow2)) * C_ + h * D_ + dcol] = (f16)val;
        }
    }
}

// ---------------------------------------------------------------------------
// Output projection: out = ctx @ Wo^T + bo, fp32 out. Same m97 structure.
// ---------------------------------------------------------------------------
__global__ __launch_bounds__(256)
void out_gemm_h(const f16* __restrict__ A, const f16* __restrict__ W,
                const float* __restrict__ bias, float* __restrict__ out)
{
    const int mb = blockIdx.x * 128;
    const int nb = blockIdx.y * 128;
    const int tid = threadIdx.x;
    const int lane = tid & 63;
    const int wid = tid >> 6;
    const int wr = wid >> 1, wc = wid & 1;
    const int l15 = lane & 15, g = lane >> 4;

    __shared__ __align__(16) f16 As[128 * 32];
    __shared__ __align__(16) f16 Bs[128 * 32];

    floatx4 acc[4][4];
#pragma unroll
    for (int m = 0; m < 4; ++m)
#pragma unroll
        for (int n = 0; n < 4; ++n) acc[m][n] = (floatx4){0.f, 0.f, 0.f, 0.f};

    for (int k0 = 0; k0 < C_; k0 += 32) {
        __syncthreads();
#pragma unroll
        for (int p = 0; p < 2; ++p) {
            int i2 = tid + 256 * p;
            int row = i2 >> 2, c4 = i2 & 3;
            gload16(&A[(size_t)(mb + row) * C_ + k0 + c4 * 8], &As[i2 * 8]);
            gload16(&W[(size_t)(nb + row) * C_ + k0 + c4 * 8], &Bs[i2 * 8]);
        }
        __syncthreads();

        half8 af[4];
#pragma unroll
        for (int m = 0; m < 4; ++m)
            af[m] = *reinterpret_cast<const half8*>(&As[(wr * 64 + m * 16 + l15) * 32 + g * 8]);
#pragma unroll
        for (int n = 0; n < 4; ++n) {
            half8 bf = *reinterpret_cast<const half8*>(&Bs[(wc * 64 + n * 16 + l15) * 32 + g * 8]);
#pragma unroll
            for (int m = 0; m < 4; ++m)
                acc[m][n] = __builtin_amdgcn_mfma_f32_16x16x32_f16(af[m], bf, acc[m][n], 0, 0, 0);
        }
    }

#pragma unroll
    for (int n = 0; n < 4; ++n) {
        int col = nb + wc * 64 + n * 16 + l15;
        float bb = bias[col];
#pragma unroll
        for (int m = 0; m < 4; ++m)
#pragma unroll
            for (int r = 0; r < 4; ++r) {
                size_t row = mb + wr * 64 + m * 16 + g * 4 + r;
                out[row * C_ + col] = acc[m][n][r] + bb;
            }
    }
}

extern "C" void kernel_launch(void* const* d_in, const int* in_sizes, int n_in,
                              void* d_out, int out_size, void* d_ws, size_t ws_size,
                              hipStream_t stream)
{
    const float* x    = (const float*)d_in[0];
    const int*   mask = (const int*)  d_in[1];
    const float* Wq   = (const float*)d_in[2];
    const float* bq   = (const float*)d_in[3];
    const float* Wk   = (const float*)d_in[4];
    const float* bk   = (const float*)d_in[5];
    const float* Wv   = (const float*)d_in[6];
    const float* bv   = (const float*)d_in[7];
    const float* Wo   = (const float*)d_in[8];
    const float* bo   = (const float*)d_in[9];
    const float* rel  = (const float*)d_in[10];
    float* out = (float*)d_out;

    const size_t XN = (size_t)B_ * S_ * C_;   // 4,194,304
    const size_t WN = (size_t)C_ * C_;        // 1,048,576

    f16* wsh  = (f16*)d_ws;
    f16* xh   = wsh;                  // 4M
    f16* Wqh  = wsh + XN;             // 4 x 1M (Wq,Wk,Wv,Wo contiguous)
    f16* Woh  = Wqh + 3 * WN;
    f16* qh   = wsh + XN + 4 * WN;    // 4M
    f16* kh   = qh + XN;
    f16* vh   = kh + XN;
    f16* ctxh = vh + XN;              // total 24M halves = 48 MB

    convert_inputs<<<8192, 256, 0, stream>>>(x, Wq, Wk, Wv, Wo, wsh);
    qkv_gemm_h<<<dim3(32, 8, 3), 256, 0, stream>>>(xh, Wqh, bq, bk, bv, qh, kh, vh);
    attn_mfma<<<dim3(32, 32), 256, 0, stream>>>(qh, kh, vh, mask, rel, ctxh);
    out_gemm_h<<<dim3(32, 8), 256, 0, stream>>>(ctxh, Woh, bo, out);
}